// Round 4
// baseline (465.880 us; speedup 1.0000x reference)
//
#include <hip/hip_runtime.h>

#define T_TOK 2048
#define H_DIM 1024
#define E_NUM 16
#define F_DIM 1024

typedef unsigned short u16;
typedef unsigned int u32;
typedef short s16x8 __attribute__((ext_vector_type(8)));
typedef float f32x4 __attribute__((ext_vector_type(4)));

__device__ __forceinline__ float b2f(u16 v) { return __uint_as_float(((u32)v) << 16); }
__device__ __forceinline__ u16 f2b(float f) {
  u32 u = __float_as_uint(f);
  return (u16)((u + 0x7fffu + ((u >> 16) & 1u)) >> 16);
}

typedef const __attribute__((address_space(1))) unsigned int ga_u32;
typedef __attribute__((address_space(3))) unsigned int ls_u32;
__device__ __forceinline__ void glds16(const void* g, void* l) {
  __builtin_amdgcn_global_load_lds((ga_u32*)(unsigned long long)g,
                                   (ls_u32*)(unsigned long long)l, 16, 0, 0);
}

#define MFMA(a, b, c) __builtin_amdgcn_mfma_f32_16x16x32_bf16(a, b, c, 0, 0, 0)

// ---------------- router ----------------
__global__ void router_kernel(const float* __restrict__ hidden, const float* __restrict__ rw,
                              int* __restrict__ counts, int* __restrict__ routing_e,
                              float* __restrict__ routing_w) {
  int t = blockIdx.x;
  int lane = threadIdx.x;  // 64
  const float* xrow = hidden + (size_t)t * H_DIM;
  float acc[E_NUM];
#pragma unroll
  for (int e = 0; e < E_NUM; ++e) acc[e] = 0.f;
  for (int j = 0; j < H_DIM / 64; ++j) {
    int h = j * 64 + lane;
    float x = xrow[h];
    const float* wr = rw + h * E_NUM;
#pragma unroll
    for (int e = 0; e < E_NUM; ++e) acc[e] += x * wr[e];
  }
#pragma unroll
  for (int e = 0; e < E_NUM; ++e) {
    acc[e] += __shfl_xor(acc[e], 32, 64);
    acc[e] += __shfl_xor(acc[e], 16, 64);
    acc[e] += __shfl_xor(acc[e], 8, 64);
    acc[e] += __shfl_xor(acc[e], 4, 64);
    acc[e] += __shfl_xor(acc[e], 2, 64);
    acc[e] += __shfl_xor(acc[e], 1, 64);
  }
  if (lane == 0) {
    float v0 = -1e30f, v1 = -1e30f;
    int i0 = 0, i1 = 0;
#pragma unroll
    for (int e = 0; e < E_NUM; ++e) {
      float v = acc[e];
      if (v > v0) { v1 = v0; i1 = i0; v0 = v; i0 = e; }
      else if (v > v1) { v1 = v; i1 = e; }
    }
    float p0 = 1.f / (1.f + __expf(v1 - v0));
    routing_e[2 * t] = i0;
    routing_e[2 * t + 1] = i1;
    routing_w[2 * t] = p0;
    routing_w[2 * t + 1] = 1.f - p0;
    atomicAdd(&counts[i0], 1);
    atomicAdd(&counts[i1], 1);
  }
}

// ---------------- scatter ----------------
__global__ void scatter_kernel(const int* __restrict__ counts, int* __restrict__ offsets,
                               const int* __restrict__ routing_e, const float* __restrict__ routing_w,
                               int* __restrict__ token_of_slot, float* __restrict__ slot_w) {
  __shared__ int offs[E_NUM];
  __shared__ int cur[E_NUM];
  int tid = threadIdx.x;
  if (tid == 0) {
    int s = 0;
    for (int e = 0; e < E_NUM; ++e) { offs[e] = s; s += counts[e]; }
  }
  __syncthreads();
  if (tid < E_NUM) { offsets[tid] = offs[tid]; cur[tid] = offs[tid]; }
  __syncthreads();
  for (int i = tid; i < 2 * T_TOK; i += 256) {
    int e = routing_e[i];
    int pos = atomicAdd(&cur[e], 1);
    token_of_slot[pos] = i >> 1;
    slot_w[pos] = routing_w[i];
  }
}

// ---------------- prepass: hidden fp32 -> bf16 hi + lo residual ----------------
__global__ void split_hidden(const float* __restrict__ h, u16* __restrict__ xh,
                             u16* __restrict__ xl) {
  int idx = (blockIdx.x * 256 + threadIdx.x) * 8;
  float4 a = *(const float4*)(h + idx);
  float4 b = *(const float4*)(h + idx + 4);
  float p[8] = {a.x, a.y, a.z, a.w, b.x, b.y, b.z, b.w};
  u16 hh[8], ll[8];
#pragma unroll
  for (int i = 0; i < 8; ++i) {
    hh[i] = f2b(p[i]);
    ll[i] = f2b(p[i] - b2f(hh[i]));
  }
  uint4 ph, pl;
  ph.x = (u32)hh[0] | ((u32)hh[1] << 16); ph.y = (u32)hh[2] | ((u32)hh[3] << 16);
  ph.z = (u32)hh[4] | ((u32)hh[5] << 16); ph.w = (u32)hh[6] | ((u32)hh[7] << 16);
  pl.x = (u32)ll[0] | ((u32)ll[1] << 16); pl.y = (u32)ll[2] | ((u32)ll[3] << 16);
  pl.z = (u32)ll[4] | ((u32)ll[5] << 16); pl.w = (u32)ll[6] | ((u32)ll[7] << 16);
  *(uint4*)(xh + idx) = ph;
  *(uint4*)(xl + idx) = pl;
}

// ---------------- prepass: batched transpose fp32 [R][C] -> bf16 [C][R] ----------------
__global__ void transpose_f32_bf16(const float* __restrict__ src, u16* __restrict__ dst,
                                   int R, int C) {
  int b = blockIdx.z;
  int c0 = blockIdx.x * 64, r0 = blockIdx.y * 64;
  const float* s = src + (size_t)b * R * C;
  u16* d = dst + (size_t)b * R * C;
  __shared__ float tile[64][65];
  int t = threadIdx.x;
  int row = t >> 2, cc = (t & 3) * 16;
#pragma unroll
  for (int i = 0; i < 4; ++i) {
    float4 v = *(const float4*)(s + (size_t)(r0 + row) * C + c0 + cc + i * 4);
    tile[row][cc + i * 4 + 0] = v.x;
    tile[row][cc + i * 4 + 1] = v.y;
    tile[row][cc + i * 4 + 2] = v.z;
    tile[row][cc + i * 4 + 3] = v.w;
  }
  __syncthreads();
  int oc = t >> 2, rr = (t & 3) * 16;
  u16 o[16];
#pragma unroll
  for (int j = 0; j < 16; ++j) o[j] = f2b(tile[rr + j][oc]);
  uint4 p0, p1;
  p0.x = (u32)o[0] | ((u32)o[1] << 16);  p0.y = (u32)o[2] | ((u32)o[3] << 16);
  p0.z = (u32)o[4] | ((u32)o[5] << 16);  p0.w = (u32)o[6] | ((u32)o[7] << 16);
  p1.x = (u32)o[8] | ((u32)o[9] << 16);  p1.y = (u32)o[10] | ((u32)o[11] << 16);
  p1.z = (u32)o[12] | ((u32)o[13] << 16); p1.w = (u32)o[14] | ((u32)o[15] << 16);
  u16* drow = d + (size_t)(c0 + oc) * R + r0 + rr;
  *(uint4*)drow = p0;
  *(uint4*)(drow + 8) = p1;
}

// XOR swizzle for 16B chunk placement: chunk perm within a row
__device__ __forceinline__ int swz(int r) { return ((r & 3) ^ ((r >> 2) & 3)) & 3; }

// ---------------- GEMM1 (fast): act[slot,f] = silu(X@Wg)*(X@Wu), bf16 out ----------------
__global__ __launch_bounds__(256, 2) void moe_gemm1_fast(
    const u16* __restrict__ xh, const u16* __restrict__ xl, const u16* __restrict__ wgu_t,
    const int* __restrict__ token_of_slot, const int* __restrict__ counts,
    const int* __restrict__ offsets, u16* __restrict__ act) {
  const int e = blockIdx.z, cnt = counts[e];
  const int m0 = blockIdx.y * 64;
  if (m0 >= cnt) return;
  const int off = offsets[e];
  const int f0 = blockIdx.x * 128;

  __shared__ u16 Xh[64 * 32], Xl[64 * 32], Bg[128 * 32], Bu[128 * 32];

  const int tid = threadIdx.x, lane = tid & 63, w = tid >> 6;
  const int q = lane >> 4, ln = lane & 15;
  const int mb = (w & 1) * 32, nb = (w >> 1) * 64;

  // staging setup (loop-invariant)
  const int lr = lane >> 2, lc = lane & 3;
  int ar = w * 16 + lr;
  int tok = token_of_slot[(m0 + ar < cnt) ? (off + m0 + ar) : off];
  int ac = (lc ^ swz(ar)) & 3;
  const u16* gxh = xh + (size_t)tok * H_DIM + ac * 8;
  const u16* gxl = xl + (size_t)tok * H_DIM + ac * 8;
  u16* dxh = &Xh[w * 512];
  u16* dxl = &Xl[w * 512];
  int br0 = w * 32 + lr, br1 = br0 + 16;
  int bc0 = (lc ^ swz(br0)) & 3, bc1 = (lc ^ swz(br1)) & 3;
  const u16* wg_base = wgu_t + ((size_t)e * 2048 + f0) * H_DIM;
  const u16* gbg0 = wg_base + (size_t)br0 * H_DIM + bc0 * 8;
  const u16* gbg1 = wg_base + (size_t)br1 * H_DIM + bc1 * 8;
  const u16* gbu0 = gbg0 + (size_t)1024 * H_DIM;
  const u16* gbu1 = gbg1 + (size_t)1024 * H_DIM;
  u16* dbg0 = &Bg[w * 1024];
  u16* dbg1 = &Bg[w * 1024 + 512];
  u16* dbu0 = &Bu[w * 1024];
  u16* dbu1 = &Bu[w * 1024 + 512];

  f32x4 zero = {0.f, 0.f, 0.f, 0.f};
  f32x4 accg[2][4], accu[2][4];
#pragma unroll
  for (int i = 0; i < 2; ++i)
#pragma unroll
    for (int j = 0; j < 4; ++j) { accg[i][j] = zero; accu[i][j] = zero; }

  for (int k0 = 0; k0 < H_DIM; k0 += 32) {
    glds16(gxh + k0, dxh);
    glds16(gxl + k0, dxl);
    glds16(gbg0 + k0, dbg0);
    glds16(gbg1 + k0, dbg1);
    glds16(gbu0 + k0, dbu0);
    glds16(gbu1 + k0, dbu1);
    __syncthreads();  // vmcnt(0) drain: LDS tiles ready

    s16x8 ah[2], al[2];
#pragma unroll
    for (int i = 0; i < 2; ++i) {
      int m = mb + i * 16 + ln;
      int p = (q ^ swz(m)) & 3;
      ah[i] = *(const s16x8*)&Xh[m * 32 + p * 8];
      al[i] = *(const s16x8*)&Xl[m * 32 + p * 8];
    }
#pragma unroll
    for (int j = 0; j < 4; ++j) {
      int n = nb + j * 16 + ln;
      int p = (q ^ swz(n)) & 3;
      s16x8 bg = *(const s16x8*)&Bg[n * 32 + p * 8];
      s16x8 bu = *(const s16x8*)&Bu[n * 32 + p * 8];
#pragma unroll
      for (int i = 0; i < 2; ++i) {
        accg[i][j] = MFMA(ah[i], bg, accg[i][j]);
        accg[i][j] = MFMA(al[i], bg, accg[i][j]);
        accu[i][j] = MFMA(ah[i], bu, accu[i][j]);
        accu[i][j] = MFMA(al[i], bu, accu[i][j]);
      }
    }
    __syncthreads();  // all waves done reading before next overwrite
  }

#pragma unroll
  for (int i = 0; i < 2; ++i) {
#pragma unroll
    for (int r = 0; r < 4; ++r) {
      int row = mb + i * 16 + q * 4 + r;
      if (m0 + row < cnt) {
        u16* arow = act + (size_t)(off + m0 + row) * F_DIM + f0 + nb + ln;
#pragma unroll
        for (int j = 0; j < 4; ++j) {
          float g = accg[i][j][r], u = accu[i][j][r];
          arow[j * 16] = f2b(g * (1.f / (1.f + __expf(-g))) * u);
        }
      }
    }
  }
}

// ---------------- GEMM2 (fast): out[tok,h] += w_slot * (act @ wd_t) ----------------
__global__ __launch_bounds__(256, 2) void moe_gemm2_fast(
    const u16* __restrict__ act, const u16* __restrict__ wd_t,
    const int* __restrict__ token_of_slot, const float* __restrict__ slot_w,
    const int* __restrict__ counts, const int* __restrict__ offsets,
    float* __restrict__ out) {
  const int e = blockIdx.z, cnt = counts[e];
  const int m0 = blockIdx.y * 64;
  if (m0 >= cnt) return;
  const int off = offsets[e];
  const int h0 = blockIdx.x * 128;

  __shared__ u16 As[64 * 32], Bd[128 * 32];

  const int tid = threadIdx.x, lane = tid & 63, w = tid >> 6;
  const int q = lane >> 4, ln = lane & 15;
  const int mb = (w & 1) * 32, nb = (w >> 1) * 64;

  const int lr = lane >> 2, lc = lane & 3;
  int ar = w * 16 + lr;
  int asl = (m0 + ar < cnt) ? (off + m0 + ar) : off;
  int ac = (lc ^ swz(ar)) & 3;
  const u16* ga = act + (size_t)asl * F_DIM + ac * 8;
  u16* da = &As[w * 512];
  int br0 = w * 32 + lr, br1 = br0 + 16;
  int bc0 = (lc ^ swz(br0)) & 3, bc1 = (lc ^ swz(br1)) & 3;
  const u16* wd_base = wd_t + ((size_t)e * 1024 + h0) * F_DIM;
  const u16* gb0 = wd_base + (size_t)br0 * F_DIM + bc0 * 8;
  const u16* gb1 = wd_base + (size_t)br1 * F_DIM + bc1 * 8;
  u16* db0 = &Bd[w * 1024];
  u16* db1 = &Bd[w * 1024 + 512];

  f32x4 zero = {0.f, 0.f, 0.f, 0.f};
  f32x4 acc[2][4];
#pragma unroll
  for (int i = 0; i < 2; ++i)
#pragma unroll
    for (int j = 0; j < 4; ++j) acc[i][j] = zero;

  for (int k0 = 0; k0 < F_DIM; k0 += 32) {
    glds16(ga + k0, da);
    glds16(gb0 + k0, db0);
    glds16(gb1 + k0, db1);
    __syncthreads();
    s16x8 af[2];
#pragma unroll
    for (int i = 0; i < 2; ++i) {
      int m = mb + i * 16 + ln;
      int p = (q ^ swz(m)) & 3;
      af[i] = *(const s16x8*)&As[m * 32 + p * 8];
    }
#pragma unroll
    for (int j = 0; j < 4; ++j) {
      int n = nb + j * 16 + ln;
      int p = (q ^ swz(n)) & 3;
      s16x8 bf = *(const s16x8*)&Bd[n * 32 + p * 8];
      acc[0][j] = MFMA(af[0], bf, acc[0][j]);
      acc[1][j] = MFMA(af[1], bf, acc[1][j]);
    }
    __syncthreads();
  }
#pragma unroll
  for (int i = 0; i < 2; ++i) {
#pragma unroll
    for (int r = 0; r < 4; ++r) {
      int row = mb + i * 16 + q * 4 + r;
      if (m0 + row < cnt) {
        int slot = off + m0 + row;
        int tok = token_of_slot[slot];
        float wgt = slot_w[slot];
        float* orow = out + (size_t)tok * H_DIM + h0 + nb + ln;
#pragma unroll
        for (int j = 0; j < 4; ++j) atomicAdd(&orow[j * 16], wgt * acc[i][j][r]);
      }
    }
  }
}

// ================= fallback path (round-3, passing): used if ws too small =================
struct f8v { float4 a, b; };

__device__ __forceinline__ void stage_w_pair(u32* __restrict__ B, int kp, int n0,
                                             const f8v& ev, const f8v& od) {
  const float* pe = (const float*)&ev;
  const float* po = (const float*)&od;
  int g0 = kp >> 2, wv = kp & 3;
#pragma unroll
  for (int i = 0; i < 8; ++i) {
    int n = n0 + i;
    u32 word = (u32)f2b(pe[i]) | ((u32)f2b(po[i]) << 16);
    B[n * 16 + (((g0 ^ (n >> 3) ^ n) & 3) << 2) + wv] = word;
  }
}
__device__ __forceinline__ s16x8 read_bfrag(const u32* __restrict__ B, int n, int q) {
  return *(const s16x8*)&B[n * 16 + (((q ^ (n >> 3) ^ n) & 3) << 2)];
}
__device__ __forceinline__ void split_pack(const float* __restrict__ p, uint4& hh, uint4& ll) {
  u16 h[8], l[8];
#pragma unroll
  for (int i = 0; i < 8; ++i) {
    h[i] = f2b(p[i]);
    l[i] = f2b(p[i] - b2f(h[i]));
  }
  hh.x = (u32)h[0] | ((u32)h[1] << 16); hh.y = (u32)h[2] | ((u32)h[3] << 16);
  hh.z = (u32)h[4] | ((u32)h[5] << 16); hh.w = (u32)h[6] | ((u32)h[7] << 16);
  ll.x = (u32)l[0] | ((u32)l[1] << 16); ll.y = (u32)l[2] | ((u32)l[3] << 16);
  ll.z = (u32)l[4] | ((u32)l[5] << 16); ll.w = (u32)l[6] | ((u32)l[7] << 16);
}

__global__ __launch_bounds__(256, 2) void moe_gemm1_fb(
    const float* __restrict__ hidden, const float* __restrict__ wgu,
    const int* __restrict__ token_of_slot, const int* __restrict__ counts,
    const int* __restrict__ offsets, float* __restrict__ act) {
  const int e = blockIdx.z, cnt = counts[e];
  const int m0 = blockIdx.y * 64;
  if (m0 >= cnt) return;
  const int off = offsets[e];
  const int f0 = blockIdx.x * 128;
  __shared__ u16 Xh[64][40];
  __shared__ u16 Xl[64][40];
  __shared__ u32 Bg[128 * 16];
  __shared__ u32 Bu[128 * 16];
  const int tid = threadIdx.x, lane = tid & 63, wave = tid >> 6;
  const int q = lane >> 4, ln = lane & 15;
  const int mb = (wave & 1) * 32, nb = (wave >> 1) * 64;
  const int xr = tid >> 2, xc = (tid & 3) * 8;
  const int tok = (m0 + xr < cnt) ? token_of_slot[off + m0 + xr] : 0;
  const float* xsrc = hidden + (size_t)tok * H_DIM + xc;
  const int kp = tid >> 4, n0 = (tid & 15) * 8;
  const float* wbase = wgu + (size_t)e * H_DIM * 2048;
  const float* wg0 = wbase + (size_t)(2 * kp) * 2048 + f0 + n0;
  const float* wu0 = wg0 + 1024;
  f32x4 zero = {0.f, 0.f, 0.f, 0.f};
  f32x4 accg[2][4], accu[2][4];
#pragma unroll
  for (int i = 0; i < 2; ++i)
#pragma unroll
    for (int j = 0; j < 4; ++j) { accg[i][j] = zero; accu[i][j] = zero; }
  for (int k0 = 0; k0 < H_DIM; k0 += 32) {
    float4 xa = *(const float4*)(xsrc + k0);
    float4 xb = *(const float4*)(xsrc + k0 + 4);
    size_t wofs = (size_t)k0 * 2048;
    f8v ge, go, ue, uo;
    ge.a = *(const float4*)(wg0 + wofs);
    ge.b = *(const float4*)(wg0 + wofs + 4);
    go.a = *(const float4*)(wg0 + wofs + 2048);
    go.b = *(const float4*)(wg0 + wofs + 2052);
    ue.a = *(const float4*)(wu0 + wofs);
    ue.b = *(const float4*)(wu0 + wofs + 4);
    uo.a = *(const float4*)(wu0 + wofs + 2048);
    uo.b = *(const float4*)(wu0 + wofs + 2052);
    __syncthreads();
    float xv[8] = {xa.x, xa.y, xa.z, xa.w, xb.x, xb.y, xb.z, xb.w};
    uint4 hh, ll;
    split_pack(xv, hh, ll);
    *(uint4*)&Xh[xr][xc] = hh;
    *(uint4*)&Xl[xr][xc] = ll;
    stage_w_pair(Bg, kp, n0, ge, go);
    stage_w_pair(Bu, kp, n0, ue, uo);
    __syncthreads();
    s16x8 ah[2], al[2];
    ah[0] = *(const s16x8*)&Xh[mb + ln][q * 8];
    ah[1] = *(const s16x8*)&Xh[mb + 16 + ln][q * 8];
    al[0] = *(const s16x8*)&Xl[mb + ln][q * 8];
    al[1] = *(const s16x8*)&Xl[mb + 16 + ln][q * 8];
#pragma unroll
    for (int j = 0; j < 4; ++j) {
      s16x8 bg = read_bfrag(Bg, nb + j * 16 + ln, q);
      s16x8 bu = read_bfrag(Bu, nb + j * 16 + ln, q);
#pragma unroll
      for (int i = 0; i < 2; ++i) {
        accg[i][j] = MFMA(ah[i], bg, accg[i][j]);
        accg[i][j] = MFMA(al[i], bg, accg[i][j]);
        accu[i][j] = MFMA(ah[i], bu, accu[i][j]);
        accu[i][j] = MFMA(al[i], bu, accu[i][j]);
      }
    }
  }
#pragma unroll
  for (int i = 0; i < 2; ++i) {
#pragma unroll
    for (int r = 0; r < 4; ++r) {
      int row = mb + i * 16 + q * 4 + r;
      if (m0 + row < cnt) {
        float* arow = act + (size_t)(off + m0 + row) * F_DIM + f0 + nb + ln;
#pragma unroll
        for (int j = 0; j < 4; ++j) {
          float g = accg[i][j][r], u = accu[i][j][r];
          arow[j * 16] = g * (1.f / (1.f + __expf(-g))) * u;
        }
      }
    }
  }
}

__global__ __launch_bounds__(256, 2) void moe_gemm2_fb(
    const float* __restrict__ act, const float* __restrict__ wd,
    const int* __restrict__ token_of_slot, const float* __restrict__ slot_w,
    const int* __restrict__ counts, const int* __restrict__ offsets,
    float* __restrict__ out) {
  const int e = blockIdx.z, cnt = counts[e];
  const int m0 = blockIdx.y * 64;
  if (m0 >= cnt) return;
  const int off = offsets[e];
  const int h0 = blockIdx.x * 128;
  __shared__ u16 Ah[64][40];
  __shared__ u16 Al[64][40];
  __shared__ u32 Bd[128 * 16];
  const int tid = threadIdx.x, lane = tid & 63, wave = tid >> 6;
  const int q = lane >> 4, ln = lane & 15;
  const int mb = (wave & 1) * 32, nb = (wave >> 1) * 64;
  const int xr = tid >> 2, xc = (tid & 3) * 8;
  const int gs = (m0 + xr < cnt) ? (off + m0 + xr) : 0;
  const float* asrc = act + (size_t)gs * F_DIM + xc;
  const int kp = tid >> 4, n0 = (tid & 15) * 8;
  const float* wd0 = wd + (size_t)e * F_DIM * H_DIM + (size_t)(2 * kp) * H_DIM + h0 + n0;
  f32x4 zero = {0.f, 0.f, 0.f, 0.f};
  f32x4 acc[2][4];
#pragma unroll
  for (int i = 0; i < 2; ++i)
#pragma unroll
    for (int j = 0; j < 4; ++j) acc[i][j] = zero;
  for (int k0 = 0; k0 < F_DIM; k0 += 32) {
    float4 aa = *(const float4*)(asrc + k0);
    float4 ab = *(const float4*)(asrc + k0 + 4);
    size_t wofs = (size_t)k0 * H_DIM;
    f8v de, dd;
    de.a = *(const float4*)(wd0 + wofs);
    de.b = *(const float4*)(wd0 + wofs + 4);
    dd.a = *(const float4*)(wd0 + wofs + 1024);
    dd.b = *(const float4*)(wd0 + wofs + 1028);
    __syncthreads();
    float av[8] = {aa.x, aa.y, aa.z, aa.w, ab.x, ab.y, ab.z, ab.w};
    uint4 hh, ll;
    split_pack(av, hh, ll);
    *(uint4*)&Ah[xr][xc] = hh;
    *(uint4*)&Al[xr][xc] = ll;
    stage_w_pair(Bd, kp, n0, de, dd);
    __syncthreads();
    s16x8 ah[2], al[2];
    ah[0] = *(const s16x8*)&Ah[mb + ln][q * 8];
    ah[1] = *(const s16x8*)&Ah[mb + 16 + ln][q * 8];
    al[0] = *(const s16x8*)&Al[mb + ln][q * 8];
    al[1] = *(const s16x8*)&Al[mb + 16 + ln][q * 8];
#pragma unroll
    for (int j = 0; j < 4; ++j) {
      s16x8 bf = read_bfrag(Bd, nb + j * 16 + ln, q);
#pragma unroll
      for (int i = 0; i < 2; ++i) {
        acc[i][j] = MFMA(ah[i], bf, acc[i][j]);
        acc[i][j] = MFMA(al[i], bf, acc[i][j]);
      }
    }
  }
#pragma unroll
  for (int i = 0; i < 2; ++i) {
#pragma unroll
    for (int r = 0; r < 4; ++r) {
      int row = mb + i * 16 + q * 4 + r;
      if (m0 + row < cnt) {
        int slot = off + m0 + row;
        int tok = token_of_slot[slot];
        float wgt = slot_w[slot];
        float* orow = out + (size_t)tok * H_DIM + h0 + nb + ln;
#pragma unroll
        for (int j = 0; j < 4; ++j) atomicAdd(&orow[j * 16], wgt * acc[i][j][r]);
      }
    }
  }
}

extern "C" void kernel_launch(void* const* d_in, const int* in_sizes, int n_in,
                              void* d_out, int out_size, void* d_ws, size_t ws_size,
                              hipStream_t stream) {
  const float* hidden = (const float*)d_in[0];  // [2048][1024] f32
  const float* rw = (const float*)d_in[1];      // [1024][16]   f32
  const float* wgu = (const float*)d_in[2];     // [16][1024][2048] f32
  const float* wd = (const float*)d_in[3];      // [16][1024][1024] f32
  float* out = (float*)d_out;                   // [2048][1024] f32
  char* ws = (char*)d_ws;

  int* counts = (int*)(ws);
  int* offsets = (int*)(ws + 256);
  int* routing_e = (int*)(ws + 1024);
  float* routing_w = (float*)(ws + 17408);
  int* token_of_slot = (int*)(ws + 33792);
  float* slot_w = (float*)(ws + 50176);

  hipMemsetAsync(counts, 0, 64, stream);
  hipMemsetAsync(out, 0, (size_t)out_size * sizeof(float), stream);
  router_kernel<<<dim3(T_TOK), dim3(64), 0, stream>>>(hidden, rw, counts, routing_e, routing_w);
  scatter_kernel<<<dim3(1), dim3(256), 0, stream>>>(counts, offsets, routing_e, routing_w,
                                                    token_of_slot, slot_w);

  const size_t NEED = 117571584ull;  // new-path workspace bytes
  if (ws_size >= NEED) {
    u16* act = (u16*)(ws + 131072);                 // 8 MB bf16 [4096][1024]
    u16* xh = (u16*)(ws + 8519680);                 // 4 MB
    u16* xl = (u16*)(ws + 12713984);                // 4 MB
    u16* wgu_t = (u16*)(ws + 16908288);             // 64 MB [16][2048][1024]
    u16* wd_t = (u16*)(ws + 84017152);              // 32 MB [16][1024][1024]

    split_hidden<<<dim3(1024), dim3(256), 0, stream>>>(hidden, xh, xl);
    transpose_f32_bf16<<<dim3(32, 16, E_NUM), dim3(256), 0, stream>>>(wgu, wgu_t, 1024, 2048);
    transpose_f32_bf16<<<dim3(16, 16, E_NUM), dim3(256), 0, stream>>>(wd, wd_t, 1024, 1024);
    moe_gemm1_fast<<<dim3(8, 32, E_NUM), dim3(256), 0, stream>>>(xh, xl, wgu_t, token_of_slot,
                                                                 counts, offsets, act);
    moe_gemm2_fast<<<dim3(8, 32, E_NUM), dim3(256), 0, stream>>>(act, wd_t, token_of_slot, slot_w,
                                                                 counts, offsets, out);
  } else {
    float* act = (float*)(ws + 131072);             // 16 MB fp32
    moe_gemm1_fb<<<dim3(8, 32, E_NUM), dim3(256), 0, stream>>>(hidden, wgu, token_of_slot, counts,
                                                               offsets, act);
    moe_gemm2_fb<<<dim3(8, 32, E_NUM), dim3(256), 0, stream>>>(act, wd, token_of_slot, slot_w,
                                                               counts, offsets, out);
  }
}